// Round 5
// baseline (99.367 us; speedup 1.0000x reference)
//
#include <hip/hip_runtime.h>

// MultiModalFusion collapses analytically:
//   q[b,n,m,s,k] = x[b,n,m,s]*A_k + bq_k   (A_k = sum_d Wq[k,d]; same for C_k/Wk, E_k/Wv)
//   scores(s,t)  = (x_s*x_t*(A.C) + x_s*(A.bk) + x_t*(C.bq) + bq.bk)/8
//   softmax over t drops terms constant in t  ->  attn = softmax_t(c_s * x_j[t]),
//       c_s = alpha*x_i[s] + gamma,  alpha=(A.C)/8, gamma=(C.bq)/8
//   mean over k of PV:  Ebar * sum_t attn*x_j[t] + bvbar
//   output[b,n,i,s] = Ebar * mean_{j!=i} y_j(c_s) + bvbar

#if __has_builtin(__builtin_amdgcn_exp2f)
#define EXP2(v) __builtin_amdgcn_exp2f(v)
#else
#define EXP2(v) exp2f(v)
#endif

static __device__ __forceinline__ float hsum4(float4 v) { return (v.x + v.y) + (v.z + v.w); }

// One wave: compute the 4 scalars into sc[0..3].
__global__ void mm_prep(const float* __restrict__ Wq, const float* __restrict__ bq,
                        const float* __restrict__ Wk, const float* __restrict__ bk,
                        const float* __restrict__ Wv, const float* __restrict__ bv,
                        float* __restrict__ sc) {
    const int k = threadIdx.x;  // 0..63
    const float4* wq4 = reinterpret_cast<const float4*>(Wq) + k * 32;
    const float4* wk4 = reinterpret_cast<const float4*>(Wk) + k * 32;
    const float4* wv4 = reinterpret_cast<const float4*>(Wv) + k * 32;
    float a = 0.f, c = 0.f, e = 0.f;
    #pragma unroll 8
    for (int d = 0; d < 32; ++d) {
        a += hsum4(wq4[d]);
        c += hsum4(wk4[d]);
        e += hsum4(wv4[d]);
    }
    float dac = a * c;         // -> alpha after reduce
    float dcq = c * bq[k];     // -> gamma after reduce
    float sbv = bv[k];
    #pragma unroll
    for (int off = 32; off > 0; off >>= 1) {
        dac += __shfl_down(dac, off, 64);
        dcq += __shfl_down(dcq, off, 64);
        e   += __shfl_down(e,   off, 64);
        sbv += __shfl_down(sbv, off, 64);
    }
    if (k == 0) {
        sc[0] = dac * 0.125f;          // alpha
        sc[1] = dcq * 0.125f;          // gamma
        sc[2] = e   * (1.0f / 64.0f);  // Ebar
        sc[3] = sbv * (1.0f / 64.0f);  // bvbar
    }
}

// One block per (b,n,i): 256 threads, thread = s.
__global__ __launch_bounds__(256) void mm_attn(const float* __restrict__ x,
                                               const float* __restrict__ sc,
                                               float* __restrict__ out) {
    __shared__ float xs[4][256];
    const int bni = blockIdx.x;          // ((b*51+n)*4 + i)
    const int i   = bni & 3;
    const int tid = threadIdx.x;
    const float* xb = x + (size_t)(bni >> 2) * 1024;
    #pragma unroll
    for (int r = 0; r < 4; ++r) xs[r][tid] = xb[r * 256 + tid];
    __syncthreads();

    const float alpha = sc[0], gamma = sc[1], Ebar = sc[2], bvbar = sc[3];
    // fold log2(e) so we can use v_exp_f32 (exp2)
    const float c2 = (alpha * xs[i][tid] + gamma) * 1.4426950408889634f;

    float acc = 0.f;
    #pragma unroll
    for (int jj = 1; jj < 4; ++jj) {
        const int j = (i + jj) & 3;                 // uniform across the block
        const float4* xj = reinterpret_cast<const float4*>(xs[j]);
        float num = 0.f, den = 0.f;
        #pragma unroll 4
        for (int t = 0; t < 64; ++t) {              // 256 elements as float4
            float4 v = xj[t];                       // LDS broadcast read
            float w0 = EXP2(c2 * v.x);
            float w1 = EXP2(c2 * v.y);
            float w2 = EXP2(c2 * v.z);
            float w3 = EXP2(c2 * v.w);
            num = fmaf(w0, v.x, fmaf(w1, v.y, fmaf(w2, v.z, fmaf(w3, v.w, num))));
            den += (w0 + w1) + (w2 + w3);
        }
        acc += num / den;
    }
    out[(size_t)bni * 256 + tid] = fmaf(Ebar * (1.0f / 3.0f), acc, bvbar);
}

extern "C" void kernel_launch(void* const* d_in, const int* in_sizes, int n_in,
                              void* d_out, int out_size, void* d_ws, size_t ws_size,
                              hipStream_t stream) {
    const float* x  = (const float*)d_in[0];
    const float* Wq = (const float*)d_in[1];
    const float* bq = (const float*)d_in[2];
    const float* Wk = (const float*)d_in[3];
    const float* bk = (const float*)d_in[4];
    const float* Wv = (const float*)d_in[5];
    const float* bv = (const float*)d_in[6];
    float* out = (float*)d_out;
    float* sc  = (float*)d_ws;   // 4 floats of scratch

    mm_prep<<<1, 64, 0, stream>>>(Wq, bq, Wk, bk, Wv, bv, sc);
    mm_attn<<<816, 256, 0, stream>>>(x, sc, out);
}